// Round 3
// baseline (654.392 us; speedup 1.0000x reference)
//
#include <hip/hip_runtime.h>
#include <stdint.h>

// RNN car-following, 256 sequential steps x 4096 vehicles; 16 veh per WG,
// 256 WGs x 256 thr (4 waves), 1 WG/CU.
// Round-3: exploit temporal redundancy of the CNN under the sliding window.
//  - conv1 pooled rows recur with period 2 -> P-ring keyed by g=t+2pp (21 slots)
//  - conv2 outputs recur with period 2 -> O2-ring keyed by a=t+2j (13 slots+4 locals)
//  - per step fresh work: 3 conv1 positions (10 MFMA), 5 conv2 jobs (60 MFMA),
//    dense2 (12 MFMA) -> 82 MFMA/step vs 196, no im2col rebuild, 3 barriers.
//  - dense2+dense1+state+output fused into wave 3 (in-wave butterfly reduce).
//  - pooling via packed u16 max (bit-exact for relu'd bf16: RNE pack is monotone).
//  - chunk-XOR swizzled P/O2 layouts: b128 frag reads ~2-4 way conflicts max.

#define PAST 25

typedef __attribute__((ext_vector_type(8))) short bf16x8;
typedef __attribute__((ext_vector_type(4))) float f32x4;
typedef unsigned short u16x2 __attribute__((ext_vector_type(2)));
#define MFMA16 __builtin_amdgcn_mfma_f32_16x16x32_bf16

static __device__ __forceinline__ uint32_t f2bf(float f) {
  union { float f; uint32_t u; } x; x.f = f;
  return (x.u + 0x7FFFu + ((x.u >> 16) & 1u)) >> 16;
}
static __device__ __forceinline__ float bf2f(uint32_t b) {
  union { uint32_t u; float f; } x; x.u = b << 16; return x.f;
}
static __device__ __forceinline__ uint32_t pkbf(float lo, float hi) {
  return f2bf(lo) | (f2bf(hi) << 16);
}
static __device__ __forceinline__ f32x4 bcast4(float v) { f32x4 r = {v, v, v, v}; return r; }

static __device__ __forceinline__ uint32_t pkmax(uint32_t a, uint32_t b) {
#if __has_builtin(__builtin_elementwise_max)
  union U { uint32_t w; u16x2 v; } x, y; x.w = a; y.w = b;
  x.v = __builtin_elementwise_max(x.v, y.v);
  return x.w;
#else
  uint32_t al = a << 16, bl = b << 16;
  uint32_t lo = (al > bl ? al : bl) >> 16;
  uint32_t ah = a & 0xffff0000u, bh = b & 0xffff0000u;
  uint32_t hi = ah > bh ? ah : bh;
  return lo | hi;
#endif
}
static __device__ __forceinline__ uint4 maxq(uint4 a, uint4 b) {
  uint4 r; r.x = pkmax(a.x, b.x); r.y = pkmax(a.y, b.y);
  r.z = pkmax(a.z, b.z); r.w = pkmax(a.w, b.w); return r;
}
static __device__ __forceinline__ int w21(int x) { if (x >= 21) x -= 21; if (x >= 21) x -= 21; return x; }
static __device__ __forceinline__ int w13(int x) { if (x >= 13) x -= 13; if (x >= 13) x -= 13; return x; }

union FragU { bf16x8 v; uint16_t u[8]; uint4 q; };

// 4224 + 23552 + 34816 = 62592 B
struct __align__(16) SMem {
  uint32_t Xcol[16][33][2];   // x-column ring (u&31): c0 = x0hi|x1<<16, c1 = x2|x0lo<<16
  uint16_t P[23 * 16 * 32];   // pooled conv1 ring: 21 ring slots (g%21) + locals 21(pp0),22(pp12)
  uint16_t O2[17 * 16 * 64];  // out2 ring: 13 slots (a%13) + locals 13(a=t),14(t+2),15(t+4),16(t+20)
};

__global__ __launch_bounds__(256, 1) void rnncf_kernel(
    const float* __restrict__ lead_states, const float* __restrict__ cur_states,
    const float* __restrict__ conv1_w, const float* __restrict__ conv1_b,
    const float* __restrict__ conv2_w, const float* __restrict__ conv2_b,
    const float* __restrict__ dense2_w, const float* __restrict__ dense2_b,
    const float* __restrict__ dense1_w, const float* __restrict__ dense1_b,
    float* __restrict__ out, int nt, int ntw) {
  __shared__ SMem sm;
  const int tid = threadIdx.x;
  const int lane = tid & 63;
  const int wid = tid >> 6;           // 0..3
  const int n = lane & 15;
  const int quad = lane >> 4;
  const int vbase = blockIdx.x * 16;

  // ---------------- phase 0: Xcol ring u=0..24 + weights + state ----------------
#pragma unroll
  for (int rep = 0; rep < 2; ++rep) {
    int idx = tid + rep * 256;
    if (idx < 400) {
      int v = idx & 15, u = idx >> 4;
      const float2 l = *(const float2*)(lead_states + ((size_t)(vbase + v) * ntw + u) * 2);
      const float2 c = *(const float2*)(cur_states + ((size_t)(vbase + v) * PAST + u) * 2);
      float x0 = (l.x - c.x) * 0.005f;
      uint32_t hi = f2bf(x0);
      uint32_t lo = f2bf(x0 - bf2f(hi));
      sm.Xcol[v][u][0] = hi | (f2bf(c.y * 0.025f) << 16);
      sm.Xcol[v][u][1] = f2bf(l.y * 0.025f) | (lo << 16);
    }
  }
  float pos_s = 0.f, spd_s = 0.f;
  float2 lead_nxt; lead_nxt.x = 0.f; lead_nxt.y = 0.f;
  if (wid == 3 && n < 4) {
    int veh = quad * 4 + n;
    const float2 c = *(const float2*)(cur_states + ((size_t)(vbase + veh) * PAST + 24) * 2);
    pos_s = c.x * 0.005f; spd_s = c.y * 0.025f;
  }

  // conv1 weights: k = cig*4+dw (cig: x0hi, x1, x2, x0lo-dup-of-x0)
  FragU B1[2];
#pragma unroll
  for (int ct = 0; ct < 2; ++ct)
#pragma unroll
    for (int jj = 0; jj < 8; ++jj) {
      int k = quad * 8 + jj;
      int dw = k & 3, cig = (k >> 2) & 3;
      float w = 0.f;
      if (k < 16 && dw < 3) {
        int ci = (cig == 3) ? 0 : cig;
        w = conv1_w[(dw * 3 + ci) * 32 + ct * 16 + n];
      }
      B1[ct].u[jj] = (uint16_t)f2bf(w);
    }
  // conv2 weights: kappa -> ci = (kap&1)*16 + (kap>>1)
  FragU B2[3][4];
#pragma unroll
  for (int dw = 0; dw < 3; ++dw)
#pragma unroll
    for (int ct = 0; ct < 4; ++ct)
#pragma unroll
      for (int jj = 0; jj < 8; ++jj) {
        int kap = quad * 8 + jj;
        int ci = (kap & 1) * 16 + (kap >> 1);
        B2[dw][ct].u[jj] = (uint16_t)f2bf(conv2_w[(dw * 32 + ci) * 64 + ct * 16 + n]);
      }
  // dense2 weights, all 12 ktiles (wave 3 consumes; uniform init is fine)
  FragU Bd[12];
#pragma unroll
  for (int kt = 0; kt < 12; ++kt)
#pragma unroll
    for (int jj = 0; jj < 8; ++jj) {
      int flat = kt * 32 + quad * 8 + jj;
      int jp = flat >> 6, kap = flat & 63;
      int co = (kap & 3) * 16 + (kap >> 2);
      Bd[kt].u[jj] = (uint16_t)f2bf((n < 10) ? dense2_w[(jp * 64 + co) * 10 + n] : 0.f);
    }
  const float b1v0 = conv1_b[n], b1v1 = conv1_b[16 + n];
  float b2v[4];
#pragma unroll
  for (int ct = 0; ct < 4; ++ct) b2v[ct] = conv2_b[ct * 16 + n];
  const float d2bv = (n < 10) ? dense2_b[n] : 0.f;
  const float wd1v = (n < 10) ? dense1_w[n] : 0.f;
  const float bd1v = dense1_b[0];

  // ---------------- helpers ----------------
  auto pIdx = [&](int s, int veh, int ch) { return ((s * 16 + veh) * 4 + ch) * 8; };
  auto oIdx = [&](int s, int veh, int ch) { return ((s * 16 + veh) * 8 + ch) * 8; };

  // build conv1 A-frag for absolute center c (this lane: veh=n, half=quad&1)
  auto build_x = [&](int c, int padL, int padR) -> FragU {
    int h = quad & 1;
    uint32_t d0 = padL ? 0u : sm.Xcol[n][(c - 1) & 31][h];
    uint32_t d1 = sm.Xcol[n][c & 31][h];
    uint32_t d2 = padR ? 0u : sm.Xcol[n][(c + 1) & 31][h];
    FragU a;
    a.q.x = __builtin_amdgcn_perm(d1, d0, 0x05040100u);
    a.q.y = d2 & 0xffffu;
    a.q.z = __builtin_amdgcn_perm(d1, d0, 0x07060302u);
    a.q.w = d2 >> 16;
    return a;
  };

  // conv1 for centers cA,cB + relu + pool -> P slot ds (kappa = 2n+ct)
  auto conv1_pair = [&](int cA, int pLA, int pRA, int cB, int pLB, int pRB, int ds) {
    FragU aA = build_x(cA, pLA, pRA);
    FragU aB = build_x(cB, pLB, pRB);
    f32x4 d0a = MFMA16(aA.v, B1[0].v, bcast4(b1v0), 0, 0, 0);
    f32x4 d0b = MFMA16(aB.v, B1[0].v, bcast4(b1v0), 0, 0, 0);
    f32x4 d1a = MFMA16(aA.v, B1[1].v, bcast4(b1v1), 0, 0, 0);
    f32x4 d1b = MFMA16(aB.v, B1[1].v, bcast4(b1v1), 0, 0, 0);
#pragma unroll
    for (int r = 0; r < 4; ++r) {
      float e0 = fmaxf(fmaxf(d0a[r], d0b[r]), 0.f);
      float e1 = fmaxf(fmaxf(d1a[r], d1b[r]), 0.f);
      int veh = quad * 4 + r;
      int ix = pIdx(ds, veh, (n >> 2) ^ (veh & 3)) + (n & 3) * 2;
      *(uint32_t*)&sm.P[ix] = pkbf(e0, e1);
    }
  };

  auto ld_P = [&](int s) -> FragU {
    FragU a; a.q = *(const uint4*)&sm.P[pIdx(s, n, quad ^ (n & 3))]; return a;
  };

  // conv2 over pool rows (P slots s0,s1,s2) + relu -> O2 slot ds (kappa2 = 4n+ct)
  auto conv2_job = [&](int s0, int s1, int s2, int ds) {
    f32x4 acc[4];
#pragma unroll
    for (int ct = 0; ct < 4; ++ct) acc[ct] = bcast4(b2v[ct]);
    int ss[3] = {s0, s1, s2};
#pragma unroll
    for (int dw = 0; dw < 3; ++dw) {
      FragU a = ld_P(ss[dw]);
#pragma unroll
      for (int ct = 0; ct < 4; ++ct) acc[ct] = MFMA16(a.v, B2[dw][ct].v, acc[ct], 0, 0, 0);
    }
#pragma unroll
    for (int r = 0; r < 4; ++r) {
      int veh = quad * 4 + r;
      float m0 = fmaxf(acc[0][r], 0.f), m1 = fmaxf(acc[1][r], 0.f);
      float m2 = fmaxf(acc[2][r], 0.f), m3 = fmaxf(acc[3][r], 0.f);
      uint2 w2; w2.x = pkbf(m0, m1); w2.y = pkbf(m2, m3);
      int ix = oIdx(ds, veh, (n >> 1) ^ (veh & 7)) + (n & 1) * 4;
      *(uint2*)&sm.O2[ix] = w2;
    }
  };

  __syncthreads();

  // ---------------- phase 1: init P-ring g=2..21 (centers 2..22) ----------------
#pragma unroll
  for (int i = 0; i < 5; ++i) {
    int j = wid + 4 * i;
    if (j < 20) {
      int g = 2 + j;
      conv1_pair(g, 0, 0, g + 1, 0, 0, g % 21);
    }
  }
  __syncthreads();

  // ---------------- phase 2: init O2-ring a=6..17 ----------------
#pragma unroll
  for (int i = 0; i < 3; ++i) {
    int a = 6 + wid + 4 * i;
    conv2_job(a % 21, (a + 2) % 21, (a + 4) % 21, a % 13);
  }
  __syncthreads();

  // ---------------- sequential steps ----------------
  int tm21 = 0, tm13 = 0;
  for (int t = 0; t < nt; ++t) {
    // P slots for this step
    const int sP2 = w21(tm21 + 2), sP4 = w21(tm21 + 4), sP6 = w21(tm21 + 6);
    const int sP8 = w21(tm21 + 8), sP18 = w21(tm21 + 18), sP20 = w21(tm21 + 20);
    const int sP22 = w21(tm21 + 22);
    const int sO6 = w13(tm13 + 6), sO8 = w13(tm13 + 8), sO10 = w13(tm13 + 10);
    const int sO12 = w13(tm13 + 12), sO14 = w13(tm13 + 14), sO16 = w13(tm13 + 16);
    const int sO18 = w13(tm13 + 18);

    // ---- stage A: fresh conv1 (3 jobs) ; wave3 prefetches next lead sample ----
    if (wid == 0) {
      conv1_pair(t, 1, 0, t + 1, 0, 0, 21);                 // pool row 0 (left pad)
    } else if (wid == 1) {
      conv1_pair(t + 22, 0, 0, t + 23, 0, 0, sP22);         // pool row 11 -> ring
    } else if (wid == 2) {
      conv1_pair(t + 24, 0, 1, t + 24, 0, 1, 22);           // pool row 12 (right pad)
    } else {
      if (n < 4) {
        int veh = quad * 4 + n;
        int ui = (t + PAST < ntw) ? (t + PAST) : (ntw - 1);
        lead_nxt = *(const float2*)(lead_states + ((size_t)(vbase + veh) * ntw + ui) * 2);
      }
    }
    __syncthreads();

    // ---- stage B: fresh conv2 (5 jobs) ----
    if (wid == 0) {
      conv2_job(21, sP2, sP4, 13);                          // j=0  (a=t, pad)
      conv2_job(sP18, sP20, sP22, sO18);                    // j=9  (a=t+18, interior -> ring)
    } else if (wid == 1) {
      conv2_job(sP2, sP4, sP6, 14);                         // j=1  (a=t+2)
    } else if (wid == 2) {
      conv2_job(sP4, sP6, sP8, 15);                         // j=2  (a=t+4)
    } else {
      conv2_job(sP20, sP22, 22, 16);                        // j=10 (a=t+20, pad)
    }
    __syncthreads();

    // ---- stage C (wave 3): dense2 + dense1 + state + output + Xcol append ----
    if (wid == 3) {
      int pa[6] = {13, 15, sO8, sO12, sO16, 16};
      int pb[6] = {14, sO6, sO10, sO14, sO18, -1};
      f32x4 acc0 = bcast4(d2bv), acc1 = bcast4(0.f);
#pragma unroll
      for (int jp = 0; jp < 6; ++jp) {
#pragma unroll
        for (int hf = 0; hf < 2; ++hf) {
          uint4 qa = *(const uint4*)&sm.O2[oIdx(pa[jp], n, (hf * 4 + quad) ^ (n & 7))];
          if (pb[jp] >= 0) {
            uint4 qb = *(const uint4*)&sm.O2[oIdx(pb[jp], n, (hf * 4 + quad) ^ (n & 7))];
            qa = maxq(qa, qb);
          }
          FragU a; a.q = qa;
          if (((jp * 2 + hf) & 1) == 0) acc0 = MFMA16(a.v, Bd[jp * 2 + hf].v, acc0, 0, 0, 0);
          else                          acc1 = MFMA16(a.v, Bd[jp * 2 + hf].v, acc1, 0, 0, 0);
        }
      }
      float s0 = fmaxf(acc0[0] + acc1[0], 0.f) * wd1v;
      float s1 = fmaxf(acc0[1] + acc1[1], 0.f) * wd1v;
      float s2 = fmaxf(acc0[2] + acc1[2], 0.f) * wd1v;
      float s3 = fmaxf(acc0[3] + acc1[3], 0.f) * wd1v;
#pragma unroll
      for (int k = 1; k <= 8; k <<= 1) {
        s0 += __shfl_xor(s0, k, 64);
        s1 += __shfl_xor(s1, k, 64);
        s2 += __shfl_xor(s2, k, 64);
        s3 += __shfl_xor(s3, k, 64);
      }
      if (n < 4) {
        float sv = (n == 0) ? s0 : (n == 1) ? s1 : (n == 2) ? s2 : s3;
        float accv = 10.f * (sv + bd1v) - 6.f;              // (MAXA-MINA)*x + MINA
        float np_s = pos_s + 0.02f * spd_s;                 // scaled pos + DT*spd
        float nsp = spd_s * 40.f + 0.1f * accv;             // raw new speed
        pos_s = np_s; spd_s = nsp * 0.025f;
        int veh = quad * 4 + n;
        float2 o2v; o2v.x = np_s * 200.f; o2v.y = nsp;
        *(float2*)(out + ((size_t)(vbase + veh) * nt + t) * 2) = o2v;
        float x0 = lead_nxt.x * 0.005f - np_s;
        uint32_t hi = f2bf(x0);
        uint32_t lo = f2bf(x0 - bf2f(hi));
        uint2 cc;
        cc.x = hi | (f2bf(spd_s) << 16);
        cc.y = f2bf(lead_nxt.y * 0.025f) | (lo << 16);
        *(uint2*)&sm.Xcol[veh][(t + PAST) & 31][0] = cc;
      }
    }
    __syncthreads();

    ++tm21; if (tm21 == 21) tm21 = 0;
    ++tm13; if (tm13 == 13) tm13 = 0;
  }
}

extern "C" void kernel_launch(void* const* d_in, const int* in_sizes, int n_in,
                              void* d_out, int out_size, void* d_ws, size_t ws_size,
                              hipStream_t stream) {
  const float* lead = (const float*)d_in[0];
  const float* cur  = (const float*)d_in[1];
  // d_in[2] = mask (unused by reference)
  const float* c1w = (const float*)d_in[3];
  const float* c1b = (const float*)d_in[4];
  const float* c2w = (const float*)d_in[5];
  const float* c2b = (const float*)d_in[6];
  const float* d2w = (const float*)d_in[7];
  const float* d2b = (const float*)d_in[8];
  const float* d1w = (const float*)d_in[9];
  const float* d1b = (const float*)d_in[10];
  float* out = (float*)d_out;

  int nveh = in_sizes[1] / (PAST * 2);   // 4096
  int ntw  = in_sizes[2] / nveh;         // nt + PAST - 1
  int nt   = ntw - PAST + 1;             // 256
  int nblocks = nveh / 16;               // 256

  rnncf_kernel<<<nblocks, 256, 0, stream>>>(lead, cur, c1w, c1b, c2w, c2b,
                                            d2w, d2b, d1w, d1b, out, nt, ntw);
}

// Round 4
// 535.765 us; speedup vs baseline: 1.2214x; 1.2214x over previous
//
#include <hip/hip_runtime.h>
#include <stdint.h>

// RNN car-following, 256 sequential steps x 4096 vehicles; 8 veh/WG, 512 WGs.
// Round-4: attack the per-step critical path (latency-bound, not throughput).
//  - ALL lead data preloaded to LDS (no per-step global loads -> no vmcnt
//    drain at barriers); outputs buffered in LDS, flushed every 64 steps.
//  - O2 ring enlarged to 17 slots: a%17 eviction (a=t+18 evicts dead a=t+1)
//    -> j1..j8 all from ring; fresh conv2 = j0, j9, j10 only.
//  - 2 barriers/step: conv2 waves compute their own fresh conv1 rows in-wave
//    (ds_write -> s_waitcnt lgkmcnt(0) -> ds_read; wid3 recomputes row11).
//  - dense wave (wid0): ring-only jp1..jp3 in stage 1, jp0/jp4/jp5 + state
//    epilogue in stage 2; accs carried across the barrier in VGPRs.

#define PAST 25
#define NTW_MAX 280

typedef __attribute__((ext_vector_type(8))) short bf16x8;
typedef __attribute__((ext_vector_type(4))) float f32x4;
typedef unsigned short u16x2 __attribute__((ext_vector_type(2)));
#define MFMA16 __builtin_amdgcn_mfma_f32_16x16x32_bf16

static __device__ __forceinline__ uint32_t f2bf(float f) {
  union { float f; uint32_t u; } x; x.f = f;
  return (x.u + 0x7FFFu + ((x.u >> 16) & 1u)) >> 16;
}
static __device__ __forceinline__ float bf2f(uint32_t b) {
  union { uint32_t u; float f; } x; x.u = b << 16; return x.f;
}
static __device__ __forceinline__ uint32_t pkbf(float lo, float hi) {
  return f2bf(lo) | (f2bf(hi) << 16);
}
static __device__ __forceinline__ f32x4 bcast4(float v) { f32x4 r = {v, v, v, v}; return r; }

static __device__ __forceinline__ uint32_t pkmax(uint32_t a, uint32_t b) {
#if __has_builtin(__builtin_elementwise_max)
  union U { uint32_t w; u16x2 v; } x, y; x.w = a; y.w = b;
  x.v = __builtin_elementwise_max(x.v, y.v);
  return x.w;
#else
  uint32_t al = a << 16, bl = b << 16;
  uint32_t lo = (al > bl ? al : bl) >> 16;
  uint32_t ah = a & 0xffff0000u, bh = b & 0xffff0000u;
  uint32_t hi = ah > bh ? ah : bh;
  return lo | hi;
#endif
}
static __device__ __forceinline__ uint4 maxq(uint4 a, uint4 b) {
  uint4 r; r.x = pkmax(a.x, b.x); r.y = pkmax(a.y, b.y);
  r.z = pkmax(a.z, b.z); r.w = pkmax(a.w, b.w); return r;
}
static __device__ __forceinline__ int w21(int x) { if (x >= 21) x -= 21; if (x >= 21) x -= 21; return x; }
static __device__ __forceinline__ int w17(int x) { if (x >= 17) x -= 17; if (x >= 17) x -= 17; return x; }
static __device__ __forceinline__ void lds_fence() {
  asm volatile("s_waitcnt lgkmcnt(0)" ::: "memory");
}

union FragU { bf16x8 v; uint16_t u[8]; uint4 q; };

// 2112 + 17920 + 12288 + 19456 + 4096 = 55872 B
struct __align__(16) SMem {
  uint32_t Xcol[8][33][2];    // x-column ring (u&31): c0 = x0hi|x1<<16, c1 = x2|x0lo<<16
  float2 lead[8][NTW_MAX];    // full lead stream (preloaded once)
  uint16_t P[24 * 8 * 32];    // pooled conv1: ring 0..20 (g%21), 21=row0, 22=row12, 23=row11copy
  uint16_t O2[19 * 8 * 64];   // out2: ring 0..16 (a%17), 17=j0, 18=j10
  float2 obuf[8][64];         // output buffer (flushed every 64 steps)
};

__global__ __launch_bounds__(256, 2) void rnncf_kernel(
    const float* __restrict__ lead_states, const float* __restrict__ cur_states,
    const float* __restrict__ conv1_w, const float* __restrict__ conv1_b,
    const float* __restrict__ conv2_w, const float* __restrict__ conv2_b,
    const float* __restrict__ dense2_w, const float* __restrict__ dense2_b,
    const float* __restrict__ dense1_w, const float* __restrict__ dense1_b,
    float* __restrict__ out, int nt, int ntw) {
  __shared__ SMem sm;
  const int tid = threadIdx.x;
  const int lane = tid & 63;
  const int wid = tid >> 6;           // 0..3
  const int n = lane & 15;
  const int quad = lane >> 4;
  const int vbase = blockIdx.x * 8;

  // ---------------- phase 0: Xcol ring + lead preload + state ----------------
  if (tid < 200) {
    int v = tid & 7, u = tid >> 3;
    const float2 l = *(const float2*)(lead_states + ((size_t)(vbase + v) * ntw + u) * 2);
    const float2 c = *(const float2*)(cur_states + ((size_t)(vbase + v) * PAST + u) * 2);
    float x0 = (l.x - c.x) * 0.005f;
    uint32_t hi = f2bf(x0);
    uint32_t lo = f2bf(x0 - bf2f(hi));
    sm.Xcol[v][u][0] = hi | (f2bf(c.y * 0.025f) << 16);
    sm.Xcol[v][u][1] = f2bf(l.y * 0.025f) | (lo << 16);
  }
#pragma unroll
  for (int v = 0; v < 8; ++v)
    for (int i = tid; i < ntw; i += 256)
      sm.lead[v][i] = *(const float2*)(lead_states + ((size_t)(vbase + v) * ntw + i) * 2);

  float pos_s = 0.f, spd_s = 0.f;
  if (wid == 0 && quad < 2 && n < 4) {
    int veh = quad * 4 + n;
    const float2 c = *(const float2*)(cur_states + ((size_t)(vbase + veh) * PAST + 24) * 2);
    pos_s = c.x * 0.005f; spd_s = c.y * 0.025f;
  }

  // ---------------- weight fragments ----------------
  FragU B1[2];
#pragma unroll
  for (int ct = 0; ct < 2; ++ct)
#pragma unroll
    for (int jj = 0; jj < 8; ++jj) {
      int k = quad * 8 + jj;
      int dw = k & 3, cig = (k >> 2) & 3;
      float w = 0.f;
      if (k < 16 && dw < 3) {
        int ci = (cig == 3) ? 0 : cig;
        w = conv1_w[(dw * 3 + ci) * 32 + ct * 16 + n];
      }
      B1[ct].u[jj] = (uint16_t)f2bf(w);
    }
  FragU B2[3][4];
#pragma unroll
  for (int dw = 0; dw < 3; ++dw)
#pragma unroll
    for (int ct = 0; ct < 4; ++ct)
#pragma unroll
      for (int jj = 0; jj < 8; ++jj) {
        int kap = quad * 8 + jj;
        int ci = (kap & 1) * 16 + (kap >> 1);
        B2[dw][ct].u[jj] = (uint16_t)f2bf(conv2_w[(dw * 32 + ci) * 64 + ct * 16 + n]);
      }
  FragU Bd[12];
#pragma unroll
  for (int kt = 0; kt < 12; ++kt)
#pragma unroll
    for (int jj = 0; jj < 8; ++jj) {
      int flat = kt * 32 + quad * 8 + jj;
      int jp = flat >> 6, kap = flat & 63;
      int co = (kap & 3) * 16 + (kap >> 2);
      Bd[kt].u[jj] = (uint16_t)f2bf((n < 10) ? dense2_w[(jp * 64 + co) * 10 + n] : 0.f);
    }
  const float b1v0 = conv1_b[n], b1v1 = conv1_b[16 + n];
  float b2v[4];
#pragma unroll
  for (int ct = 0; ct < 4; ++ct) b2v[ct] = conv2_b[ct * 16 + n];
  const float d2bv = (n < 10) ? dense2_b[n] : 0.f;
  const float wd1v = (n < 10) ? dense1_w[n] : 0.f;
  const float bd1v = dense1_b[0];

  // ---------------- helpers ----------------
  auto pIdx = [&](int s, int veh, int ch) { return ((s * 8 + veh) * 4 + ch) * 8; };
  auto oIdx = [&](int s, int veh, int ch) { return ((s * 8 + veh) * 8 + ch) * 8; };

  auto build_x = [&](int c, int padL, int padR) -> FragU {
    int h = quad & 1, v8 = n & 7;
    uint32_t d0 = padL ? 0u : sm.Xcol[v8][(c - 1) & 31][h];
    uint32_t d1 = sm.Xcol[v8][c & 31][h];
    uint32_t d2 = padR ? 0u : sm.Xcol[v8][(c + 1) & 31][h];
    FragU a;
    a.q.x = __builtin_amdgcn_perm(d1, d0, 0x05040100u);
    a.q.y = d2 & 0xffffu;
    a.q.z = __builtin_amdgcn_perm(d1, d0, 0x07060302u);
    a.q.w = d2 >> 16;
    return a;
  };

  auto conv1_pair = [&](int cA, int pLA, int pRA, int cB, int pLB, int pRB, int ds) {
    FragU aA = build_x(cA, pLA, pRA);
    FragU aB = build_x(cB, pLB, pRB);
    f32x4 d0a = MFMA16(aA.v, B1[0].v, bcast4(b1v0), 0, 0, 0);
    f32x4 d0b = MFMA16(aB.v, B1[0].v, bcast4(b1v0), 0, 0, 0);
    f32x4 d1a = MFMA16(aA.v, B1[1].v, bcast4(b1v1), 0, 0, 0);
    f32x4 d1b = MFMA16(aB.v, B1[1].v, bcast4(b1v1), 0, 0, 0);
    if (quad < 2) {
#pragma unroll
      for (int r = 0; r < 4; ++r) {
        float e0 = fmaxf(fmaxf(d0a[r], d0b[r]), 0.f);
        float e1 = fmaxf(fmaxf(d1a[r], d1b[r]), 0.f);
        int veh = quad * 4 + r;
        *(uint32_t*)&sm.P[pIdx(ds, veh, (n >> 2) ^ (veh & 3)) + (n & 3) * 2] = pkbf(e0, e1);
      }
    }
  };

  auto conv1_single = [&](int c, int padL, int padR, int ds) {
    FragU a = build_x(c, padL, padR);
    f32x4 d0 = MFMA16(a.v, B1[0].v, bcast4(b1v0), 0, 0, 0);
    f32x4 d1 = MFMA16(a.v, B1[1].v, bcast4(b1v1), 0, 0, 0);
    if (quad < 2) {
#pragma unroll
      for (int r = 0; r < 4; ++r) {
        float e0 = fmaxf(d0[r], 0.f), e1 = fmaxf(d1[r], 0.f);
        int veh = quad * 4 + r;
        *(uint32_t*)&sm.P[pIdx(ds, veh, (n >> 2) ^ (veh & 3)) + (n & 3) * 2] = pkbf(e0, e1);
      }
    }
  };

  auto ld_P = [&](int s) -> FragU {
    FragU a; a.q = *(const uint4*)&sm.P[pIdx(s, n & 7, quad ^ (n & 3))]; return a;
  };

  auto conv2_job = [&](int s0, int s1, int s2, int ds) {
    f32x4 acc[4];
#pragma unroll
    for (int ct = 0; ct < 4; ++ct) acc[ct] = bcast4(b2v[ct]);
    int ss[3] = {s0, s1, s2};
#pragma unroll
    for (int dw = 0; dw < 3; ++dw) {
      FragU a = ld_P(ss[dw]);
#pragma unroll
      for (int ct = 0; ct < 4; ++ct) acc[ct] = MFMA16(a.v, B2[dw][ct].v, acc[ct], 0, 0, 0);
    }
    if (quad < 2) {
#pragma unroll
      for (int r = 0; r < 4; ++r) {
        int veh = quad * 4 + r;
        float m0 = fmaxf(acc[0][r], 0.f), m1 = fmaxf(acc[1][r], 0.f);
        float m2 = fmaxf(acc[2][r], 0.f), m3 = fmaxf(acc[3][r], 0.f);
        uint2 w2; w2.x = pkbf(m0, m1); w2.y = pkbf(m2, m3);
        *(uint2*)&sm.O2[oIdx(ds, veh, (n >> 1) ^ (veh & 7)) + (n & 1) * 4] = w2;
      }
    }
  };

  auto dense_jp = [&](int pa, int pb, int jp, f32x4& a0, f32x4& a1) {
#pragma unroll
    for (int hf = 0; hf < 2; ++hf) {
      uint4 qa = *(const uint4*)&sm.O2[oIdx(pa, n & 7, (hf * 4 + quad) ^ (n & 7))];
      if (pb >= 0) {
        uint4 qb = *(const uint4*)&sm.O2[oIdx(pb, n & 7, (hf * 4 + quad) ^ (n & 7))];
        qa = maxq(qa, qb);
      }
      FragU a; a.q = qa;
      if (hf == 0) a0 = MFMA16(a.v, Bd[jp * 2].v, a0, 0, 0, 0);
      else         a1 = MFMA16(a.v, Bd[jp * 2 + 1].v, a1, 0, 0, 0);
    }
  };

  auto flush_out = [&](int t0, int cnt) {
    int vv = lane >> 3;
    int s0 = (lane & 7) * 8;
#pragma unroll
    for (int k = 0; k < 8; ++k) {
      int s = s0 + k;
      if (s < cnt) {
        float2 d = sm.obuf[vv][s];
        *(float2*)(out + ((size_t)(vbase + vv) * nt + t0 + s) * 2) = d;
      }
    }
  };

  __syncthreads();

  // ---------------- phase 1: P ring init g=2..21 ----------------
#pragma unroll
  for (int i = 0; i < 5; ++i) {
    int g = 2 + wid + 4 * i;
    conv1_pair(g, 0, 0, g + 1, 0, 0, g % 21);
  }
  __syncthreads();

  // ---------------- phase 2: O2 ring init a=2..17 ----------------
#pragma unroll
  for (int i = 0; i < 4; ++i) {
    int a = 2 + wid + 4 * i;
    conv2_job(a % 21, (a + 2) % 21, (a + 4) % 21, a % 17);
  }
  __syncthreads();

  // ---------------- sequential steps (2 barriers each) ----------------
  int tm21 = 0, tm17 = 0;
  for (int t = 0; t < nt; ++t) {
    const int sP2 = w21(tm21 + 2), sP4 = w21(tm21 + 4);
    const int sP18 = w21(tm21 + 18), sP20 = w21(tm21 + 20), sP22 = w21(tm21 + 22);
    const int sO2 = w17(tm17 + 2), sO4 = w17(tm17 + 4), sO6 = w17(tm17 + 6);
    const int sO8 = w17(tm17 + 8), sO10 = w17(tm17 + 10), sO12 = w17(tm17 + 12);
    const int sO14 = w17(tm17 + 14), sO16 = w17(tm17 + 16), sO18 = w17(tm17 + 18);

    f32x4 acc0, acc1;

    // ---- stage 1 ----
    if (wid == 0) {
      acc0 = bcast4(d2bv); acc1 = bcast4(0.f);
      dense_jp(sO4, sO6, 1, acc0, acc1);     // jp1 = max(j2, j3)   (ring)
      dense_jp(sO8, sO10, 2, acc0, acc1);    // jp2 = max(j4, j5)   (ring)
      dense_jp(sO12, sO14, 3, acc0, acc1);   // jp3 = max(j6, j7)   (ring)
    } else if (wid == 1) {
      if ((t & 63) == 0 && t > 0) flush_out(t - 64, 64);
      conv1_pair(t, 1, 0, t + 1, 0, 0, 21);                // pool row 0 (pad)
      lds_fence();
      conv2_job(21, sP2, sP4, 17);                         // j=0 -> local 17
    } else if (wid == 2) {
      conv1_pair(t + 22, 0, 0, t + 23, 0, 0, sP22);        // pool row 11 -> ring
      lds_fence();
      conv2_job(sP18, sP20, sP22, sO18);                   // j=9 -> ring
    } else {
      conv1_pair(t + 22, 0, 0, t + 23, 0, 0, 23);          // row 11 copy (local)
      conv1_single(t + 24, 0, 1, 22);                      // pool row 12 (pad)
      lds_fence();
      conv2_job(sP20, 23, 22, 18);                         // j=10 -> local 18
    }
    __syncthreads();

    // ---- stage 2: dense finish + state (wid0) ----
    if (wid == 0) {
      dense_jp(17, sO2, 0, acc0, acc1);      // jp0 = max(j0, j1)
      dense_jp(sO16, sO18, 4, acc0, acc1);   // jp4 = max(j8, j9)
      dense_jp(18, -1, 5, acc0, acc1);       // jp5 = j10
      float s0 = fmaxf(acc0[0] + acc1[0], 0.f) * wd1v;
      float s1 = fmaxf(acc0[1] + acc1[1], 0.f) * wd1v;
      float s2 = fmaxf(acc0[2] + acc1[2], 0.f) * wd1v;
      float s3 = fmaxf(acc0[3] + acc1[3], 0.f) * wd1v;
#pragma unroll
      for (int k = 1; k <= 8; k <<= 1) {
        s0 += __shfl_xor(s0, k, 64);
        s1 += __shfl_xor(s1, k, 64);
        s2 += __shfl_xor(s2, k, 64);
        s3 += __shfl_xor(s3, k, 64);
      }
      if (quad < 2 && n < 4) {
        int veh = quad * 4 + n;
        float sv = (n == 0) ? s0 : (n == 1) ? s1 : (n == 2) ? s2 : s3;
        float accv = 10.f * (sv + bd1v) - 6.f;            // (MAXA-MINA)*x + MINA
        float np_s = pos_s + 0.02f * spd_s;               // scaled pos + DT*spd
        float nsp = spd_s * 40.f + 0.1f * accv;           // raw new speed
        pos_s = np_s; spd_s = nsp * 0.025f;
        float2 o2v; o2v.x = np_s * 200.f; o2v.y = nsp;
        sm.obuf[veh][t & 63] = o2v;
        int ui = t + PAST; if (ui > ntw - 1) ui = ntw - 1;
        float2 ln = sm.lead[veh][ui];
        float x0 = ln.x * 0.005f - np_s;
        uint32_t hi = f2bf(x0);
        uint32_t lo = f2bf(x0 - bf2f(hi));
        sm.Xcol[veh][(t + PAST) & 31][0] = hi | (f2bf(spd_s) << 16);
        sm.Xcol[veh][(t + PAST) & 31][1] = f2bf(ln.y * 0.025f) | (lo << 16);
      }
    }
    __syncthreads();

    ++tm21; if (tm21 == 21) tm21 = 0;
    ++tm17; if (tm17 == 17) tm17 = 0;
  }

  // final output flush
  if (wid == 1) {
    int t0 = (nt > 64) ? ((nt - 1) & ~63) : 0;
    flush_out(t0, nt - t0);
  }
}

extern "C" void kernel_launch(void* const* d_in, const int* in_sizes, int n_in,
                              void* d_out, int out_size, void* d_ws, size_t ws_size,
                              hipStream_t stream) {
  const float* lead = (const float*)d_in[0];
  const float* cur  = (const float*)d_in[1];
  // d_in[2] = mask (unused by reference)
  const float* c1w = (const float*)d_in[3];
  const float* c1b = (const float*)d_in[4];
  const float* c2w = (const float*)d_in[5];
  const float* c2b = (const float*)d_in[6];
  const float* d2w = (const float*)d_in[7];
  const float* d2b = (const float*)d_in[8];
  const float* d1w = (const float*)d_in[9];
  const float* d1b = (const float*)d_in[10];
  float* out = (float*)d_out;

  int nveh = in_sizes[1] / (PAST * 2);   // 4096
  int ntw  = in_sizes[2] / nveh;         // nt + PAST - 1 (<= NTW_MAX)
  int nt   = ntw - PAST + 1;             // 256
  int nblocks = nveh / 8;                // 512

  rnncf_kernel<<<nblocks, 256, 0, stream>>>(lead, cur, c1w, c1b, c2w, c2b,
                                            d2w, d2b, d1w, d1b, out, nt, ntw);
}